// Round 11
// baseline (93.173 us; speedup 1.0000x reference)
//
#include <hip/hip_runtime.h>
#include <math.h>

#define NU_ 12000
#define NI_ 16000
#define NPU 12288   // padded Et stride
#define NPI 16384   // padded Et stride
#define DD 64
#define BB 1024
#define KC 256      // K-chunk (floats) per block iteration
#define SPL 8

typedef unsigned short ushort_t;
typedef __bf16 bf16x8 __attribute__((ext_vector_type(8)));
typedef float  f32x4  __attribute__((ext_vector_type(4)));
typedef float  f4v    __attribute__((ext_vector_type(4)));
typedef unsigned short ushort4v __attribute__((ext_vector_type(4)));

static __device__ __forceinline__ ushort_t f2bf(float f) {
    __bf16 h = (__bf16)f;
    return __builtin_bit_cast(unsigned short, h);
}
static __device__ __forceinline__ f4v ntload(const void* p) {
    return __builtin_nontemporal_load((const f4v*)p);   // nt: no L2 allocate
}

// ---------------------------------------------------------------------------
// Kernel 0 (merged): transpose + cast BOTH embed tables E[N][64] f32 ->
// Et[64][Np] bf16, zero-padded cols N..Np. Block 0 also zeroes the ticket.
// ---------------------------------------------------------------------------
__global__ __launch_bounds__(256) void gde_transpose2(
    const float* __restrict__ ue, const float* __restrict__ ie,
    ushort_t* __restrict__ EtU, ushort_t* __restrict__ EtI,
    unsigned int* __restrict__ ticket)
{
    if (blockIdx.x == 0 && threadIdx.x == 0) *ticket = 0u;

    const float* E; ushort_t* Et; int N, Np, n0;
    if ((int)blockIdx.x < NPU / 64) {
        E = ue; Et = EtU; N = NU_; Np = NPU; n0 = blockIdx.x * 64;
    } else {
        E = ie; Et = EtI; N = NI_; Np = NPI; n0 = (blockIdx.x - NPU / 64) * 64;
    }

    __shared__ ushort_t Ls[64][65];
    const int tid = threadIdx.x;
    const int dg  = tid & 15;
    const int nr  = tid >> 4;
#pragma unroll
    for (int nn = 0; nn < 4; ++nn) {
        const int nl = nn * 16 + nr;
        const int n  = n0 + nl;
        float4 v = make_float4(0.f, 0.f, 0.f, 0.f);
        if (n < N) v = *(const float4*)(E + (size_t)n * DD + dg * 4);
        Ls[nl][dg * 4 + 0] = f2bf(v.x);
        Ls[nl][dg * 4 + 1] = f2bf(v.y);
        Ls[nl][dg * 4 + 2] = f2bf(v.z);
        Ls[nl][dg * 4 + 3] = f2bf(v.w);
    }
    __syncthreads();
    const int d   = tid & 63;
    const int nl0 = (tid >> 6) * 16;
#pragma unroll
    for (int g = 0; g < 4; ++g) {
        ushort4v t;
#pragma unroll
        for (int i = 0; i < 4; ++i) t[i] = Ls[nl0 + g * 4 + i][d];
        *(ushort4v*)(Et + (size_t)d * Np + n0 + nl0 + g * 4) = t;
    }
}

// ---------------------------------------------------------------------------
// Kernel 1: gathered+masked GEMM — FROZEN R10 structure (best: 92.4us).
// 3 blocks/CU, LPT 1D grid, counted-vmcnt raw-barrier pipeline, cross-wave
// LDS reduction epilogue (one P slice per block). NT stores for P.
// ---------------------------------------------------------------------------
__global__ __launch_bounds__(256, 3) void gde_gemm(
    const float* __restrict__ L_u, const float* __restrict__ L_i,
    const ushort_t* __restrict__ EtU, const ushort_t* __restrict__ EtI,
    const float* __restrict__ mu,  const float* __restrict__ mp,
    const float* __restrict__ mn,
    const int* __restrict__ user, const int* __restrict__ pos,
    const int* __restrict__ nega,
    float* __restrict__ P, int S)
{
    __shared__ __align__(16) char smem[4 * 32 * 65 * 4];

    const int bid = blockIdx.x;
    int j, idx;
    if (bid < 512) { j = 1 + (bid >> 8); idx = bid & 255; }
    else           { j = 0;              idx = bid - 512; }
    const int rt = idx & 31;
    const int s  = idx >> 5;

    const int tid = threadIdx.x;
    const int w   = tid >> 6;
    const int l   = tid & 63;

    const float* L; const ushort_t* Et; const float* M; const int* idx_;
    int N, Np;
    if (j == 0)      { L = L_u; Et = EtU; M = mu; idx_ = user; N = NU_; Np = NPU; }
    else if (j == 1) { L = L_i; Et = EtI; M = mp; idx_ = pos;  N = NI_; Np = NPI; }
    else             { L = L_i; Et = EtI; M = mn; idx_ = nega; N = NI_; Np = NPI; }

    const int base = rt * 32;
    unsigned int Loff[8], Moff[8];
#pragma unroll
    for (int r = 0; r < 8; ++r) {
        const int row = base + w * 8 + r;
        Loff[r] = (unsigned int)idx_[row] * (unsigned int)(N * 4);
        Moff[r] = (unsigned int)row * (unsigned int)(N * 4);
    }

    const int dcol = l & 15;
    const int g4   = l >> 4;
    const ushort_t* EbBase = Et + (size_t)dcol * Np;
    const size_t dfs = (size_t)16 * Np;

    f32x4 acc[8];
#pragma unroll
    for (int i = 0; i < 8; ++i) acc[i] = (f32x4){0.f, 0.f, 0.f, 0.f};

    const int nc  = (N + KC - 1) / KC;
    const int kb0 = (s * nc) / S;
    const int kb1 = ((s + 1) * nc) / S;

    f4v La[8], Ma[8];
#pragma unroll
    for (int r = 0; r < 8; ++r) { La[r] = (f4v){0.f,0.f,0.f,0.f}; Ma[r] = La[r]; }

    {
        const int kg = kb0 * KC + 4 * l;
        if (kg < N) {
            const size_t boff = (size_t)kg * 4u;
#pragma unroll
            for (int r = 0; r < 8; ++r) {
                La[r] = ntload((const char*)L + Loff[r] + boff);
                Ma[r] = ntload((const char*)M + Moff[r] + boff);
            }
        }
    }

    for (int kb = kb0; kb < kb1; ++kb) {
#pragma unroll
        for (int r = 0; r < 8; ++r) {
            const int row = w * 8 + r;
            ushort4v t;
            t[0] = (Ma[r][0] >= 0.1f) ? f2bf(La[r][0]) : (ushort_t)0;
            t[1] = (Ma[r][1] >= 0.1f) ? f2bf(La[r][1]) : (ushort_t)0;
            t[2] = (Ma[r][2] >= 0.1f) ? f2bf(La[r][2]) : (ushort_t)0;
            t[3] = (Ma[r][3] >= 0.1f) ? f2bf(La[r][3]) : (ushort_t)0;
            *(ushort4v*)(smem + (row << 9) + ((l * 8) ^ ((row & 7) << 4))) = t;
        }

        bf16x8 bfr0[4];
        {
            const int kk = kb * KC + (2 * w) * 32 + 8 * g4;
#pragma unroll
            for (int df = 0; df < 4; ++df)
                bfr0[df] = *(const bf16x8*)(EbBase + df * dfs + kk);
        }
        asm volatile("" ::: "memory");

        if (kb + 1 < kb1) {
            const int kg = (kb + 1) * KC + 4 * l;
            if (kg < N) {
                const size_t boff = (size_t)kg * 4u;
#pragma unroll
                for (int r = 0; r < 8; ++r) {
                    La[r] = ntload((const char*)L + Loff[r] + boff);
                    Ma[r] = ntload((const char*)M + Moff[r] + boff);
                }
            }
        }

        asm volatile("s_waitcnt lgkmcnt(0)" ::: "memory");
        __builtin_amdgcn_s_barrier();
        asm volatile("" ::: "memory");

        {
            const int ks0 = 2 * w;
            const int cb0 = 64 * ks0 + 16 * g4;
            const int r0 = dcol, r1 = 16 + dcol;
            const bf16x8 af0 = *(const bf16x8*)(smem + (r0 << 9) + (cb0 ^ ((r0 & 7) << 4)));
            const bf16x8 af1 = *(const bf16x8*)(smem + (r1 << 9) + (cb0 ^ ((r1 & 7) << 4)));

            bf16x8 bfr1[4];
            {
                const int kk = kb * KC + (2 * w + 1) * 32 + 8 * g4;
#pragma unroll
                for (int df = 0; df < 4; ++df)
                    bfr1[df] = *(const bf16x8*)(EbBase + df * dfs + kk);
            }

            acc[0] = __builtin_amdgcn_mfma_f32_16x16x32_bf16(af0, bfr0[0], acc[0], 0, 0, 0);
            acc[1] = __builtin_amdgcn_mfma_f32_16x16x32_bf16(af0, bfr0[1], acc[1], 0, 0, 0);
            acc[2] = __builtin_amdgcn_mfma_f32_16x16x32_bf16(af0, bfr0[2], acc[2], 0, 0, 0);
            acc[3] = __builtin_amdgcn_mfma_f32_16x16x32_bf16(af0, bfr0[3], acc[3], 0, 0, 0);
            acc[4] = __builtin_amdgcn_mfma_f32_16x16x32_bf16(af1, bfr0[0], acc[4], 0, 0, 0);
            acc[5] = __builtin_amdgcn_mfma_f32_16x16x32_bf16(af1, bfr0[1], acc[5], 0, 0, 0);
            acc[6] = __builtin_amdgcn_mfma_f32_16x16x32_bf16(af1, bfr0[2], acc[6], 0, 0, 0);
            acc[7] = __builtin_amdgcn_mfma_f32_16x16x32_bf16(af1, bfr0[3], acc[7], 0, 0, 0);

            const int cb1 = 64 * (ks0 + 1) + 16 * g4;
            const bf16x8 ag0 = *(const bf16x8*)(smem + (r0 << 9) + (cb1 ^ ((r0 & 7) << 4)));
            const bf16x8 ag1 = *(const bf16x8*)(smem + (r1 << 9) + (cb1 ^ ((r1 & 7) << 4)));

            acc[0] = __builtin_amdgcn_mfma_f32_16x16x32_bf16(ag0, bfr1[0], acc[0], 0, 0, 0);
            acc[1] = __builtin_amdgcn_mfma_f32_16x16x32_bf16(ag0, bfr1[1], acc[1], 0, 0, 0);
            acc[2] = __builtin_amdgcn_mfma_f32_16x16x32_bf16(ag0, bfr1[2], acc[2], 0, 0, 0);
            acc[3] = __builtin_amdgcn_mfma_f32_16x16x32_bf16(ag0, bfr1[3], acc[3], 0, 0, 0);
            acc[4] = __builtin_amdgcn_mfma_f32_16x16x32_bf16(ag1, bfr1[0], acc[4], 0, 0, 0);
            acc[5] = __builtin_amdgcn_mfma_f32_16x16x32_bf16(ag1, bfr1[1], acc[5], 0, 0, 0);
            acc[6] = __builtin_amdgcn_mfma_f32_16x16x32_bf16(ag1, bfr1[2], acc[6], 0, 0, 0);
            acc[7] = __builtin_amdgcn_mfma_f32_16x16x32_bf16(ag1, bfr1[3], acc[7], 0, 0, 0);
        }

        asm volatile("" ::: "memory");
        __builtin_amdgcn_s_barrier();
        asm volatile("" ::: "memory");
    }

    // ---- cross-wave reduction -> ONE P slice per block (NT stores)
    __syncthreads();
    float* Rs = (float*)smem;
#pragma unroll
    for (int fi = 0; fi < 8; ++fi) {
#pragma unroll
        for (int ri = 0; ri < 4; ++ri) {
            const int row = ((fi >> 2) << 4) + g4 * 4 + ri;
            const int col = ((fi & 3) << 4) + dcol;
            Rs[(w * 32 + row) * 65 + col] = acc[fi][ri];
        }
    }
    __syncthreads();
    {
        const int row  = tid >> 3;
        const int colg = (tid & 7) * 8;
        float v[8];
#pragma unroll
        for (int i = 0; i < 8; ++i) {
            v[i] = Rs[(0 * 32 + row) * 65 + colg + i]
                 + Rs[(1 * 32 + row) * 65 + colg + i]
                 + Rs[(2 * 32 + row) * 65 + colg + i]
                 + Rs[(3 * 32 + row) * 65 + colg + i];
        }
        float* Pb = P + ((size_t)(j * S + s) * BB + base + row) * DD + colg;
        __builtin_nontemporal_store(((f4v){v[0], v[1], v[2], v[3]}), (f4v*)(Pb + 0));
        __builtin_nontemporal_store(((f4v){v[4], v[5], v[6], v[7]}), (f4v*)(Pb + 4));
    }
}

// ---------------------------------------------------------------------------
// Kernel 2: finalize + last-block reduce (fused). 256 blocks x 4 rows.
// Each block writes one partial; the last block (ticket) sums all 256 in
// fixed order -> deterministic scalar output.
// ---------------------------------------------------------------------------
__global__ __launch_bounds__(256) void gde_finalize(
    const float* __restrict__ P, int Seff,
    float* __restrict__ blockSum, unsigned int* __restrict__ ticket,
    float* __restrict__ out)
{
    const int w    = threadIdx.x >> 6;
    const int b    = blockIdx.x * 4 + w;
    const int lane = threadIdx.x & 63;
    const size_t joff = (size_t)Seff * BB * DD;

    float fu = 0.f, fp_ = 0.f, fn = 0.f;
    for (int s = 0; s < Seff; ++s) {
        const size_t base = ((size_t)s * BB + b) * DD + lane;
        fu  += P[base];
        fp_ += P[base + joff];
        fn  += P[base + 2 * joff];
    }

    float rp = fu * fp_;
    float rn = fu * fn;
    float rg = fu * fu + fp_ * fp_ + fn * fn;
#pragma unroll
    for (int o = 32; o > 0; o >>= 1) {
        rp += __shfl_xor(rp, o);
        rn += __shfl_xor(rn, o);
        rg += __shfl_xor(rg, o);
    }

    __shared__ float ws[4];
    __shared__ bool last;
    if (lane == 0) {
        const float sn = 1.0f / (1.0f + expf(-rn));
        const float wt = 1.0f - log10f(1.0f - fminf(sn, 0.99f));
        const float x  = rp - wt * rn;
        const float t  = -x;   // -log(sigmoid(x)) = softplus(-x), finite
        const float term = fmaxf(t, 0.0f) + log1pf(expf(-fabsf(t)));
        ws[w] = term + 0.01f * rg;
    }
    __syncthreads();
    if (threadIdx.x == 0) {
        blockSum[blockIdx.x] = ws[0] + ws[1] + ws[2] + ws[3];
        __threadfence();
        const unsigned int t = atomicAdd(ticket, 1u);
        last = (t == (unsigned int)(gridDim.x - 1));
    }
    __syncthreads();

    if (last) {
        __threadfence();
        __shared__ float sm[256];
        const int t = threadIdx.x;
        sm[t] = blockSum[t];             // gridDim.x == 256
        __syncthreads();
        for (int o = 128; o > 0; o >>= 1) {
            if (t < o) sm[t] += sm[t + o];
            __syncthreads();
        }
        if (t == 0) out[0] = sm[0] / (float)BB;
    }
}

extern "C" void kernel_launch(void* const* d_in, const int* in_sizes, int n_in,
                              void* d_out, int out_size, void* d_ws, size_t ws_size,
                              hipStream_t stream)
{
    const float* L_u = (const float*)d_in[0];
    const float* L_i = (const float*)d_in[1];
    const float* ue  = (const float*)d_in[2];
    const float* ie  = (const float*)d_in[3];
    const float* mu  = (const float*)d_in[4];
    const float* mp  = (const float*)d_in[5];
    const float* mn  = (const float*)d_in[6];
    const int* user  = (const int*)d_in[7];
    const int* pos   = (const int*)d_in[8];
    const int* nega  = (const int*)d_in[9];
    float* out = (float*)d_out;

    const size_t etU_b  = (size_t)DD * NPU * 2;
    const size_t etI_b  = (size_t)DD * NPI * 2;
    const size_t slice  = (size_t)3 * BB * DD * 4;    // per-slice P bytes
    const int S = SPL;                                 // 8 slices (6.3 MB)

    float*        P      = (float*)d_ws;
    ushort_t*     EtU    = (ushort_t*)((char*)d_ws + (size_t)S * slice);
    ushort_t*     EtI    = (ushort_t*)((char*)EtU + etU_b);
    float*        bsum   = (float*)((char*)EtI + etI_b);
    unsigned int* ticket = (unsigned int*)(bsum + 256);

    gde_transpose2<<<dim3(NPU / 64 + NPI / 64), dim3(256), 0, stream>>>(
        ue, ie, EtU, EtI, ticket);

    gde_gemm<<<dim3(32 * SPL * 3), dim3(256), 0, stream>>>(
        L_u, L_i, EtU, EtI, mu, mp, mn, user, pos, nega, P, S);

    gde_finalize<<<dim3(BB / 4), dim3(256), 0, stream>>>(
        P, S, bsum, ticket, out);
}